// Round 1
// baseline (2953.361 us; speedup 1.0000x reference)
//
#include <hip/hip_runtime.h>

// Problem constants
// B=16, T=64, HW=7 (HW2=49), D=768, N=12, C=64, 3D=2304
// x:(B,T,7,7,768) fp32; out:(B,T,768) fp32

// ---------------------------------------------------------------------------
// K0: transpose Wp[d*3136 + c*49 + hw]  ->  WpT[(hw*64 + c)*64 + d]
// ---------------------------------------------------------------------------
__global__ void wp_transpose_k(const float* __restrict__ src, float* __restrict__ dst) {
  int o = blockIdx.x * 256 + threadIdx.x;          // 200704 total
  if (o >= 200704) return;
  int d  = o & 63;
  int k  = o >> 6;          // k = hw*64 + c
  int c  = k & 63;
  int hw = k >> 6;          // 0..48
  dst[o] = src[d * 3136 + c * 49 + hw];
}

// ---------------------------------------------------------------------------
// K1/K4: C[m,n] = sum_k A[m,k]*B[k,n] (+bias[n])
// 64x64 tile, BK=16, 256 threads, 4x4 per thread. M%64==0, N%64==0, K%16==0.
// ---------------------------------------------------------------------------
__global__ __launch_bounds__(256) void gemm_f32_k(
    const float* __restrict__ A, const float* __restrict__ Bm,
    const float* __restrict__ bias, float* __restrict__ Cm,
    int M, int Nn, int K) {
  __shared__ float As[16][68];   // [k][m], padded
  __shared__ float Bs[16][64];   // [k][n]
  const int tid = threadIdx.x;
  const int ty = tid >> 4, tx = tid & 15;
  const int m0 = blockIdx.y * 64, n0 = blockIdx.x * 64;

  const int la_m = tid >> 2;              // 0..63
  const int la_k = (tid & 3) << 2;        // 0,4,8,12
  const int lb_k = tid >> 4;              // 0..15
  const int lb_n = (tid & 15) << 2;       // 0..60

  const float* Ap = A + (size_t)(m0 + la_m) * K + la_k;
  const float* Bp = Bm + (size_t)lb_k * Nn + n0 + lb_n;

  float acc[4][4];
#pragma unroll
  for (int i = 0; i < 4; ++i)
#pragma unroll
    for (int j = 0; j < 4; ++j) acc[i][j] = 0.f;

  for (int k0 = 0; k0 < K; k0 += 16) {
    float4 av = *(const float4*)(Ap + k0);
    float4 bv = *(const float4*)(Bp + (size_t)k0 * Nn);
    As[la_k + 0][la_m] = av.x;
    As[la_k + 1][la_m] = av.y;
    As[la_k + 2][la_m] = av.z;
    As[la_k + 3][la_m] = av.w;
    *(float4*)&Bs[lb_k][lb_n] = bv;
    __syncthreads();
#pragma unroll
    for (int kk = 0; kk < 16; ++kk) {
      float af[4], bf[4];
      *(float4*)af = *(const float4*)&As[kk][ty << 2];
      *(float4*)bf = *(const float4*)&Bs[kk][tx << 2];
#pragma unroll
      for (int i = 0; i < 4; ++i)
#pragma unroll
        for (int j = 0; j < 4; ++j) acc[i][j] += af[i] * bf[j];
    }
    __syncthreads();
  }

  float bb[4] = {0.f, 0.f, 0.f, 0.f};
  if (bias) {
#pragma unroll
    for (int j = 0; j < 4; ++j) bb[j] = bias[n0 + (tx << 2) + j];
  }
#pragma unroll
  for (int i = 0; i < 4; ++i) {
    float4 o;
    o.x = acc[i][0] + bb[0];
    o.y = acc[i][1] + bb[1];
    o.z = acc[i][2] + bb[2];
    o.w = acc[i][3] + bb[3];
    *(float4*)(Cm + (size_t)(m0 + (ty << 2) + i) * Nn + n0 + (tx << 2)) = o;
  }
}

// ---------------------------------------------------------------------------
// K2: pooling projection + bias + LayerNorm, fused.
// Block = (n, p, bi). Computes out[t(64), d(64)] = sum_{hw,c} qkv[bi, t, hw, p, n, c] * Wp[d,c,hw]
// K = 49*64 = 3136, tiled as 49 tiles of 64 (one hw each).
// ---------------------------------------------------------------------------
__global__ __launch_bounds__(256) void pool_ln_k(
    const float* __restrict__ qkvB, const float* __restrict__ WpT, int b0,
    const float* __restrict__ bq, const float* __restrict__ bk, const float* __restrict__ bv,
    const float* __restrict__ gq, const float* __restrict__ gk, const float* __restrict__ gv,
    const float* __restrict__ beq, const float* __restrict__ bek, const float* __restrict__ bev,
    float* __restrict__ oq, float* __restrict__ ok_, float* __restrict__ ov) {
  __shared__ float As[64][68];   // [c][t] during K-loop; reused as [t][d] for LN
  __shared__ float Bs[64][64];   // [c][d]
  __shared__ float mu_s[64], rs_s[64];

  const int n = blockIdx.x, p = blockIdx.y, bi = blockIdx.z;
  const int b = b0 + bi;
  const int tid = threadIdx.x;
  const int ty = tid >> 4, tx = tid & 15;

  const float* bias = (p == 0) ? bq : (p == 1) ? bk : bv;
  const float* g    = (p == 0) ? gq : (p == 1) ? gk : gv;
  const float* be   = (p == 0) ? beq : (p == 1) ? bek : bev;
  float* outp       = (p == 0) ? oq : (p == 1) ? ok_ : ov;
  const float* wp = WpT + (size_t)p * 200704;

  const int la_t = tid >> 2;          // 0..63
  const int la_c = (tid & 3) << 4;    // 0,16,32,48
  const size_t abase = ((size_t)bi * 3136 + (size_t)la_t * 49) * 2304
                       + (size_t)p * 768 + (size_t)n * 64 + la_c;

  float acc[4][4];
#pragma unroll
  for (int i = 0; i < 4; ++i)
#pragma unroll
    for (int j = 0; j < 4; ++j) acc[i][j] = 0.f;

  for (int hw = 0; hw < 49; ++hw) {
    // A tile: 64 t x 64 c (this hw)
    const float* ap = qkvB + abase + (size_t)hw * 2304;
    float avv[16];
    *(float4*)(avv + 0)  = *(const float4*)(ap + 0);
    *(float4*)(avv + 4)  = *(const float4*)(ap + 4);
    *(float4*)(avv + 8)  = *(const float4*)(ap + 8);
    *(float4*)(avv + 12) = *(const float4*)(ap + 12);
#pragma unroll
    for (int ii = 0; ii < 16; ++ii) As[la_c + ii][la_t] = avv[ii];
    // B tile: contiguous 4096 floats
    const float4* bsrc = (const float4*)(wp + (size_t)hw * 4096);
    float4* bdst = (float4*)&Bs[0][0];
#pragma unroll
    for (int r = 0; r < 4; ++r) bdst[tid + 256 * r] = bsrc[tid + 256 * r];
    __syncthreads();
#pragma unroll 8
    for (int kk = 0; kk < 64; ++kk) {
      float af[4], bf[4];
      *(float4*)af = *(const float4*)&As[kk][ty << 2];
      *(float4*)bf = *(const float4*)&Bs[kk][tx << 2];
#pragma unroll
      for (int i = 0; i < 4; ++i)
#pragma unroll
        for (int j = 0; j < 4; ++j) acc[i][j] += af[i] * bf[j];
    }
    __syncthreads();
  }

  // bias + stash into LDS for LayerNorm stats
  float bsv[4], gvv[4], bevv[4];
#pragma unroll
  for (int j = 0; j < 4; ++j) {
    int d = (tx << 2) + j;
    bsv[j] = bias[d]; gvv[j] = g[d]; bevv[j] = be[d];
  }
  float val[4][4];
#pragma unroll
  for (int i = 0; i < 4; ++i)
#pragma unroll
    for (int j = 0; j < 4; ++j) {
      val[i][j] = acc[i][j] + bsv[j];
      As[(ty << 2) + i][(tx << 2) + j] = val[i][j];
    }
  __syncthreads();
  if (tid < 64) {
    float s = 0.f;
#pragma unroll 8
    for (int c = 0; c < 64; ++c) s += As[tid][c];
    float m = s * (1.f / 64.f);
    float v2 = 0.f;
#pragma unroll 8
    for (int c = 0; c < 64; ++c) { float dl = As[tid][c] - m; v2 += dl * dl; }
    mu_s[tid] = m;
    rs_s[tid] = rsqrtf(v2 * (1.f / 64.f) + 1e-5f);
  }
  __syncthreads();
#pragma unroll
  for (int i = 0; i < 4; ++i) {
    int t = (ty << 2) + i;
    float m = mu_s[t], r = rs_s[t];
    float4 o;
    o.x = (val[i][0] - m) * r * gvv[0] + bevv[0];
    o.y = (val[i][1] - m) * r * gvv[1] + bevv[1];
    o.z = (val[i][2] - m) * r * gvv[2] + bevv[2];
    o.w = (val[i][3] - m) * r * gvv[3] + bevv[3];
    *(float4*)(outp + ((size_t)(b * 12 + n) * 64 + t) * 64 + (tx << 2)) = o;
  }
}

// ---------------------------------------------------------------------------
// K3: fused attention per (b,n): S = scale*qk^T + q@Rt^T, softmax, O = P@v + q.
// Writes directly in (b, t, n, c) layout for the final projection.
// ---------------------------------------------------------------------------
__global__ __launch_bounds__(256) void attention_k(
    const float* __restrict__ qpool, const float* __restrict__ kpool,
    const float* __restrict__ vpool, const float* __restrict__ relp,
    float* __restrict__ aout) {
  __shared__ float qs[64 * 65];
  __shared__ float ks[64 * 65];   // reused for P after S phase
  __shared__ float vs[64 * 65];

  const int n = blockIdx.x, b = blockIdx.y;
  const int tid = threadIdx.x;
  const size_t base = ((size_t)b * 12 + n) * 4096;

  for (int idx = tid; idx < 4096; idx += 256) {
    int t = idx >> 6, c = idx & 63;
    qs[t * 65 + c] = qpool[base + idx];
    ks[t * 65 + c] = kpool[base + idx];
    vs[t * 65 + c] = vpool[base + idx];
  }
  __syncthreads();

  const int t = tid >> 2, sg = tid & 3;
  const float scale = 0.125f;    // C^-0.5

  float sv[16];
#pragma unroll
  for (int j = 0; j < 16; ++j) sv[j] = 0.f;
  for (int c = 0; c < 64; ++c) {
    float qv = qs[t * 65 + c];
#pragma unroll
    for (int j = 0; j < 16; ++j) {
      int s = (sg << 4) + j;
      sv[j] += qv * (scale * ks[s * 65 + c] + relp[(t - s + 63) * 64 + c]);
    }
  }
  // softmax over s (64) within groups of 4 lanes
  float mx = sv[0];
#pragma unroll
  for (int j = 1; j < 16; ++j) mx = fmaxf(mx, sv[j]);
  mx = fmaxf(mx, __shfl_xor(mx, 1));
  mx = fmaxf(mx, __shfl_xor(mx, 2));
  float sum = 0.f;
#pragma unroll
  for (int j = 0; j < 16; ++j) { sv[j] = __expf(sv[j] - mx); sum += sv[j]; }
  sum += __shfl_xor(sum, 1);
  sum += __shfl_xor(sum, 2);
  float inv = 1.f / sum;
  __syncthreads();                       // all S-phase reads of ks done
#pragma unroll
  for (int j = 0; j < 16; ++j) ks[t * 65 + (sg << 4) + j] = sv[j] * inv;
  __syncthreads();

  // O = P @ v + q
  const int c0 = sg << 4;
  float outv[16];
#pragma unroll
  for (int j = 0; j < 16; ++j) outv[j] = qs[t * 65 + c0 + j];
  for (int s = 0; s < 64; ++s) {
    float pv = ks[t * 65 + s];
#pragma unroll
    for (int j = 0; j < 16; ++j) outv[j] += pv * vs[s * 65 + c0 + j];
  }
  float* dst = aout + ((size_t)b * 64 + t) * 768 + n * 64 + c0;
#pragma unroll
  for (int j = 0; j < 16; ++j) dst[j] = outv[j];
}

// ---------------------------------------------------------------------------
extern "C" void kernel_launch(void* const* d_in, const int* in_sizes, int n_in,
                              void* d_out, int out_size, void* d_ws, size_t ws_size,
                              hipStream_t stream) {
  const float* x     = (const float*)d_in[0];
  const float* Wqkv  = (const float*)d_in[1];
  const float* Wpq   = (const float*)d_in[2];
  const float* bpq   = (const float*)d_in[3];
  const float* Wpk   = (const float*)d_in[4];
  const float* bpk   = (const float*)d_in[5];
  const float* Wpv   = (const float*)d_in[6];
  const float* bpv   = (const float*)d_in[7];
  const float* gq    = (const float*)d_in[8];
  const float* beq   = (const float*)d_in[9];
  const float* gk    = (const float*)d_in[10];
  const float* bek   = (const float*)d_in[11];
  const float* gv    = (const float*)d_in[12];
  const float* bev   = (const float*)d_in[13];
  const float* relp  = (const float*)d_in[14];
  const float* Wproj = (const float*)d_in[15];
  const float* bproj = (const float*)d_in[16];
  float* out = (float*)d_out;

  float* ws = (float*)d_ws;
  size_t off = 0;
  float* WpT   = ws + off; off += 3ull * 200704;   // 602112
  float* qpool = ws + off; off += 786432;
  float* kpool = ws + off; off += 786432;
  float* vpool = ws + off; off += 786432;
  float* aout  = ws + off; off += 786432;
  float* qkvB  = ws + off;

  size_t availf = (ws_size / 4 > off) ? (ws_size / 4 - off) : 0;
  const size_t perb = 3136ull * 2304ull;   // qkv floats per batch element
  int nb = (int)(availf / perb);
  if (nb < 1) nb = 1;
  if (nb > 16) nb = 16;

  wp_transpose_k<<<784, 256, 0, stream>>>(Wpq, WpT);
  wp_transpose_k<<<784, 256, 0, stream>>>(Wpk, WpT + 200704);
  wp_transpose_k<<<784, 256, 0, stream>>>(Wpv, WpT + 401408);

  for (int b0 = 0; b0 < 16; b0 += nb) {
    int cur = (16 - b0) < nb ? (16 - b0) : nb;
    gemm_f32_k<<<dim3(36, cur * 49), 256, 0, stream>>>(
        x + (size_t)b0 * 3136 * 768, Wqkv, nullptr, qkvB, cur * 3136, 2304, 768);
    pool_ln_k<<<dim3(12, 3, cur), 256, 0, stream>>>(
        qkvB, WpT, b0, bpq, bpk, bpv, gq, gk, gv, beq, bek, bev,
        qpool, kpool, vpool);
  }

  attention_k<<<dim3(12, 16), 256, 0, stream>>>(qpool, kpool, vpool, relp, aout);

  gemm_f32_k<<<dim3(12, 16), 256, 0, stream>>>(aout, Wproj, bproj, out, 1024, 768, 768);
}

// Round 2
// 750.657 us; speedup vs baseline: 3.9344x; 3.9344x over previous
//
#include <hip/hip_runtime.h>

// B=16, T=64, HW=7 (HW2=49), D=768, N=12, C=64, 3D=2304
// x:(B,T,7,7,768) fp32; out:(B,T,768) fp32

typedef __attribute__((ext_vector_type(8))) short bf16x8;
typedef __attribute__((ext_vector_type(4))) float f32x4;

#define AS1U(p) ((const __attribute__((address_space(1))) unsigned int*)(p))
#define AS3U(p) ((__attribute__((address_space(3))) unsigned int*)(p))

__device__ __forceinline__ unsigned short cvt_bf16(float x) {
  union { float f; unsigned int u; } v; v.f = x;
  unsigned int r = v.u + 0x7fffu + ((v.u >> 16) & 1u);
  return (unsigned short)(r >> 16);
}

// ---------------------------------------------------------------------------
// x fp32 -> bf16 (8 elems/thread)
// ---------------------------------------------------------------------------
__global__ __launch_bounds__(256) void cvt_x_k(const float* __restrict__ src,
                                               unsigned short* __restrict__ dst, int n8) {
  int i = blockIdx.x * 256 + threadIdx.x;
  if (i >= n8) return;
  const float4* s = (const float4*)src + (size_t)i * 2;
  float4 a = s[0], b = s[1];
  ushort4 r0 = { cvt_bf16(a.x), cvt_bf16(a.y), cvt_bf16(a.z), cvt_bf16(a.w) };
  ushort4 r1 = { cvt_bf16(b.x), cvt_bf16(b.y), cvt_bf16(b.z), cvt_bf16(b.w) };
  ushort4* d = (ushort4*)dst + (size_t)i * 2;
  d[0] = r0; d[1] = r1;
}

// ---------------------------------------------------------------------------
// Wqkv [768][2304] fp32 -> WqkvT [2304][768] bf16 (LDS tiled transpose)
// ---------------------------------------------------------------------------
__global__ __launch_bounds__(256) void transpose_cvt_k(const float* __restrict__ src,
                                                       unsigned short* __restrict__ dst) {
  __shared__ float tl[32][33];
  int k0 = blockIdx.x * 32, n0 = blockIdx.y * 32;
  int tx = threadIdx.x & 31, ty = threadIdx.x >> 5;
#pragma unroll
  for (int r = 0; r < 32; r += 8)
    tl[ty + r][tx] = src[(size_t)(k0 + ty + r) * 2304 + n0 + tx];
  __syncthreads();
#pragma unroll
  for (int r = 0; r < 32; r += 8)
    dst[(size_t)(n0 + ty + r) * 768 + k0 + tx] = cvt_bf16(tl[tx][ty + r]);
}

// ---------------------------------------------------------------------------
// Wp [d*3136 + c*49 + hw] fp32 -> WpTT [(hw*64+d)*64 + c] bf16 (per p)
// ---------------------------------------------------------------------------
__global__ __launch_bounds__(256) void wp_cvt_k(const float* __restrict__ src,
                                                unsigned short* __restrict__ dst) {
  int o = blockIdx.x * 256 + threadIdx.x;   // 200704
  if (o >= 200704) return;
  int c = o & 63, d = (o >> 6) & 63, hw = o >> 12;
  dst[o] = cvt_bf16(src[d * 3136 + c * 49 + hw]);
}

// ---------------------------------------------------------------------------
// MFMA GEMM: C[m][n] = sum_k A[m][k] * Bt[n][k], bf16 in, bf16 out.
// 128x128 tile, BK=32, 256 threads (4 waves 2x2), m97 structure.
// ---------------------------------------------------------------------------
__global__ __launch_bounds__(256) void gemm_bt_mfma_k(
    const unsigned short* __restrict__ A, const unsigned short* __restrict__ Bt,
    unsigned short* __restrict__ Cb, int M, int Nn, int K) {
  __shared__ unsigned short As[128 * 32];
  __shared__ unsigned short Bs[128 * 32];
  const int tid = threadIdx.x;
  const int wave = tid >> 6, lane = tid & 63;
  const int quad = lane >> 4, l16 = lane & 15;
  const int m0 = blockIdx.y * 128, n0 = blockIdx.x * 128;
  const int wm = (wave >> 1) * 64, wn = (wave & 1) * 64;

  // staging: each instr covers 16 rows x 64B; lane -> row=lane>>2, seg=(lane&3)*8
  const int srow = lane >> 2;
  const int scol = (lane & 3) * 8;
  const unsigned short* Ag0 = A + (size_t)(m0 + wave * 16 + srow) * K + scol;
  const unsigned short* Ag1 = Ag0 + (size_t)64 * K;
  const unsigned short* Bg0 = Bt + (size_t)(n0 + wave * 16 + srow) * K + scol;
  const unsigned short* Bg1 = Bg0 + (size_t)64 * K;
  unsigned short* Asw0 = &As[(wave * 16) * 32];
  unsigned short* Asw1 = &As[(64 + wave * 16) * 32];
  unsigned short* Bsw0 = &Bs[(wave * 16) * 32];
  unsigned short* Bsw1 = &Bs[(64 + wave * 16) * 32];

  f32x4 acc[4][4];
#pragma unroll
  for (int i = 0; i < 4; ++i)
#pragma unroll
    for (int j = 0; j < 4; ++j) acc[i][j] = (f32x4){0.f, 0.f, 0.f, 0.f};

  for (int k0 = 0; k0 < K; k0 += 32) {
    __builtin_amdgcn_global_load_lds(AS1U(Ag0 + k0), AS3U(Asw0), 16, 0, 0);
    __builtin_amdgcn_global_load_lds(AS1U(Ag1 + k0), AS3U(Asw1), 16, 0, 0);
    __builtin_amdgcn_global_load_lds(AS1U(Bg0 + k0), AS3U(Bsw0), 16, 0, 0);
    __builtin_amdgcn_global_load_lds(AS1U(Bg1 + k0), AS3U(Bsw1), 16, 0, 0);
    __syncthreads();
    bf16x8 af[4], bfr[4];
#pragma unroll
    for (int f = 0; f < 4; ++f) {
      af[f]  = *(const bf16x8*)&As[(wm + f * 16 + l16) * 32 + quad * 8];
      bfr[f] = *(const bf16x8*)&Bs[(wn + f * 16 + l16) * 32 + quad * 8];
    }
#pragma unroll
    for (int i = 0; i < 4; ++i)
#pragma unroll
      for (int j = 0; j < 4; ++j)
        acc[i][j] = __builtin_amdgcn_mfma_f32_16x16x32_bf16(af[i], bfr[j], acc[i][j], 0, 0, 0);
    __syncthreads();
  }

#pragma unroll
  for (int i = 0; i < 4; ++i)
#pragma unroll
    for (int j = 0; j < 4; ++j)
#pragma unroll
      for (int r = 0; r < 4; ++r) {
        int row = m0 + wm + i * 16 + quad * 4 + r;
        int col = n0 + wn + j * 16 + l16;
        Cb[(size_t)row * Nn + col] = cvt_bf16(acc[i][j][r]);
      }
}

// ---------------------------------------------------------------------------
// Pool + bias + LayerNorm, MFMA. Block (n, p, b): out[t=64][d=64] =
// sum_{hw,c} qkvb[b,t,hw,p,n,c] * WpTT[p,hw,d,c].  XOR-swizzled LDS chunks.
// ---------------------------------------------------------------------------
__global__ __launch_bounds__(256) void pool_ln_mfma_k(
    const unsigned short* __restrict__ qkvb, const unsigned short* __restrict__ WpTT,
    const float* __restrict__ bq, const float* __restrict__ bk, const float* __restrict__ bv,
    const float* __restrict__ gq, const float* __restrict__ gk, const float* __restrict__ gv,
    const float* __restrict__ beq, const float* __restrict__ bek, const float* __restrict__ bev,
    float* __restrict__ oq, float* __restrict__ ok_, float* __restrict__ ov) {
  __shared__ unsigned short As[64 * 64];   // [t][c] chunk-swizzled
  __shared__ unsigned short Bs[64 * 64];   // [d][c] chunk-swizzled
  __shared__ float Ln[64 * 65];
  __shared__ float mu_s[64], rs_s[64];

  const int n = blockIdx.x, p = blockIdx.y, b = blockIdx.z;
  const int tid = threadIdx.x;
  const int wave = tid >> 6, lane = tid & 63;
  const int quad = lane >> 4, l16 = lane & 15;
  const int wm = (wave >> 1) * 32, wn = (wave & 1) * 32;

  // staging: instr covers 8 rows x 128B; lane -> row=lane>>3, slot=lane&7
  const int arow = lane >> 3, aslot = lane & 7;
  const int r0 = wave * 8 + arow, r1 = r0 + 32;
  const int g0 = ((aslot ^ (r0 & 7)) * 8);   // ushort offset of global chunk
  const int g1 = ((aslot ^ (r1 & 7)) * 8);
  const size_t abase = ((size_t)b * 3136) * 2304 + (size_t)p * 768 + (size_t)n * 64;
  const unsigned short* Ag0 = qkvb + abase + (size_t)r0 * 49 * 2304 + g0;
  const unsigned short* Ag1 = qkvb + abase + (size_t)r1 * 49 * 2304 + g1;
  const unsigned short* WpB = WpTT + (size_t)p * 49 * 4096;
  const unsigned short* Bg0 = WpB + r0 * 64 + g0;
  const unsigned short* Bg1 = WpB + r1 * 64 + g1;
  unsigned short* Asw0 = &As[(wave * 8) * 64];
  unsigned short* Asw1 = &As[(32 + wave * 8) * 64];
  unsigned short* Bsw0 = &Bs[(wave * 8) * 64];
  unsigned short* Bsw1 = &Bs[(32 + wave * 8) * 64];

  f32x4 acc[2][2];
#pragma unroll
  for (int i = 0; i < 2; ++i)
#pragma unroll
    for (int j = 0; j < 2; ++j) acc[i][j] = (f32x4){0.f, 0.f, 0.f, 0.f};

  for (int hw = 0; hw < 49; ++hw) {
    __builtin_amdgcn_global_load_lds(AS1U(Ag0 + (size_t)hw * 2304), AS3U(Asw0), 16, 0, 0);
    __builtin_amdgcn_global_load_lds(AS1U(Ag1 + (size_t)hw * 2304), AS3U(Asw1), 16, 0, 0);
    __builtin_amdgcn_global_load_lds(AS1U(Bg0 + (size_t)hw * 4096), AS3U(Bsw0), 16, 0, 0);
    __builtin_amdgcn_global_load_lds(AS1U(Bg1 + (size_t)hw * 4096), AS3U(Bsw1), 16, 0, 0);
    __syncthreads();
#pragma unroll
    for (int h = 0; h < 2; ++h) {
      bf16x8 af[2], bfr[2];
#pragma unroll
      for (int f = 0; f < 2; ++f) {
        int ra = wm + f * 16 + l16;
        af[f] = *(const bf16x8*)&As[ra * 64 + (((h * 4 + quad) ^ (ra & 7)) * 8)];
        int rb = wn + f * 16 + l16;
        bfr[f] = *(const bf16x8*)&Bs[rb * 64 + (((h * 4 + quad) ^ (rb & 7)) * 8)];
      }
#pragma unroll
      for (int i = 0; i < 2; ++i)
#pragma unroll
        for (int j = 0; j < 2; ++j)
          acc[i][j] = __builtin_amdgcn_mfma_f32_16x16x32_bf16(af[i], bfr[j], acc[i][j], 0, 0, 0);
    }
    __syncthreads();
  }

  const float* bias = (p == 0) ? bq : (p == 1) ? bk : bv;
  const float* g    = (p == 0) ? gq : (p == 1) ? gk : gv;
  const float* be   = (p == 0) ? beq : (p == 1) ? bek : bev;
  float* outp       = (p == 0) ? oq : (p == 1) ? ok_ : ov;

#pragma unroll
  for (int i = 0; i < 2; ++i)
#pragma unroll
    for (int j = 0; j < 2; ++j)
#pragma unroll
      for (int r = 0; r < 4; ++r) {
        int t = wm + i * 16 + quad * 4 + r;
        int d = wn + j * 16 + l16;
        Ln[t * 65 + d] = acc[i][j][r] + bias[d];
      }
  __syncthreads();
  if (tid < 64) {
    float s = 0.f;
#pragma unroll 8
    for (int c = 0; c < 64; ++c) s += Ln[tid * 65 + c];
    float m = s * (1.f / 64.f);
    float v2 = 0.f;
#pragma unroll 8
    for (int c = 0; c < 64; ++c) { float dl = Ln[tid * 65 + c] - m; v2 += dl * dl; }
    mu_s[tid] = m;
    rs_s[tid] = rsqrtf(v2 * (1.f / 64.f) + 1e-5f);
  }
  __syncthreads();
  {
    int t = tid >> 2, d0 = (tid & 3) * 16;
    float m = mu_s[t], rv = rs_s[t];
    float* dst = outp + ((size_t)(b * 12 + n) * 64 + t) * 64 + d0;
#pragma unroll
    for (int j = 0; j < 16; j += 4) {
      float4 o;
      o.x = (Ln[t * 65 + d0 + j + 0] - m) * rv * g[d0 + j + 0] + be[d0 + j + 0];
      o.y = (Ln[t * 65 + d0 + j + 1] - m) * rv * g[d0 + j + 1] + be[d0 + j + 1];
      o.z = (Ln[t * 65 + d0 + j + 2] - m) * rv * g[d0 + j + 2] + be[d0 + j + 2];
      o.w = (Ln[t * 65 + d0 + j + 3] - m) * rv * g[d0 + j + 3] + be[d0 + j + 3];
      *(float4*)(dst + j) = o;
    }
  }
}

// ---------------------------------------------------------------------------
// fp32 GEMM (final projection only): C[m,n] = sum_k A[m,k]*B[k,n] + bias[n]
// ---------------------------------------------------------------------------
__global__ __launch_bounds__(256) void gemm_f32_k(
    const float* __restrict__ A, const float* __restrict__ Bm,
    const float* __restrict__ bias, float* __restrict__ Cm,
    int M, int Nn, int K) {
  __shared__ float As[16][68];
  __shared__ float Bs[16][64];
  const int tid = threadIdx.x;
  const int ty = tid >> 4, tx = tid & 15;
  const int m0 = blockIdx.y * 64, n0 = blockIdx.x * 64;

  const int la_m = tid >> 2;
  const int la_k = (tid & 3) << 2;
  const int lb_k = tid >> 4;
  const int lb_n = (tid & 15) << 2;

  const float* Ap = A + (size_t)(m0 + la_m) * K + la_k;
  const float* Bp = Bm + (size_t)lb_k * Nn + n0 + lb_n;

  float acc[4][4];
#pragma unroll
  for (int i = 0; i < 4; ++i)
#pragma unroll
    for (int j = 0; j < 4; ++j) acc[i][j] = 0.f;

  for (int k0 = 0; k0 < K; k0 += 16) {
    float4 av = *(const float4*)(Ap + k0);
    float4 bv = *(const float4*)(Bp + (size_t)k0 * Nn);
    As[la_k + 0][la_m] = av.x;
    As[la_k + 1][la_m] = av.y;
    As[la_k + 2][la_m] = av.z;
    As[la_k + 3][la_m] = av.w;
    *(float4*)&Bs[lb_k][lb_n] = bv;
    __syncthreads();
#pragma unroll
    for (int kk = 0; kk < 16; ++kk) {
      float af[4], bf[4];
      *(float4*)af = *(const float4*)&As[kk][ty << 2];
      *(float4*)bf = *(const float4*)&Bs[kk][tx << 2];
#pragma unroll
      for (int i = 0; i < 4; ++i)
#pragma unroll
        for (int j = 0; j < 4; ++j) acc[i][j] += af[i] * bf[j];
    }
    __syncthreads();
  }

  float bb[4] = {0.f, 0.f, 0.f, 0.f};
  if (bias) {
#pragma unroll
    for (int j = 0; j < 4; ++j) bb[j] = bias[n0 + (tx << 2) + j];
  }
#pragma unroll
  for (int i = 0; i < 4; ++i) {
    float4 o;
    o.x = acc[i][0] + bb[0];
    o.y = acc[i][1] + bb[1];
    o.z = acc[i][2] + bb[2];
    o.w = acc[i][3] + bb[3];
    *(float4*)(Cm + (size_t)(m0 + (ty << 2) + i) * Nn + n0 + (tx << 2)) = o;
  }
}

// ---------------------------------------------------------------------------
// Fused attention per (b,n), fp32 (unchanged from R1).
// ---------------------------------------------------------------------------
__global__ __launch_bounds__(256) void attention_k(
    const float* __restrict__ qpool, const float* __restrict__ kpool,
    const float* __restrict__ vpool, const float* __restrict__ relp,
    float* __restrict__ aout) {
  __shared__ float qs[64 * 65];
  __shared__ float ks[64 * 65];
  __shared__ float vs[64 * 65];

  const int n = blockIdx.x, b = blockIdx.y;
  const int tid = threadIdx.x;
  const size_t base = ((size_t)b * 12 + n) * 4096;

  for (int idx = tid; idx < 4096; idx += 256) {
    int t = idx >> 6, c = idx & 63;
    qs[t * 65 + c] = qpool[base + idx];
    ks[t * 65 + c] = kpool[base + idx];
    vs[t * 65 + c] = vpool[base + idx];
  }
  __syncthreads();

  const int t = tid >> 2, sg = tid & 3;
  const float scale = 0.125f;

  float sv[16];
#pragma unroll
  for (int j = 0; j < 16; ++j) sv[j] = 0.f;
  for (int c = 0; c < 64; ++c) {
    float qv = qs[t * 65 + c];
#pragma unroll
    for (int j = 0; j < 16; ++j) {
      int s = (sg << 4) + j;
      sv[j] += qv * (scale * ks[s * 65 + c] + relp[(t - s + 63) * 64 + c]);
    }
  }
  float mx = sv[0];
#pragma unroll
  for (int j = 1; j < 16; ++j) mx = fmaxf(mx, sv[j]);
  mx = fmaxf(mx, __shfl_xor(mx, 1));
  mx = fmaxf(mx, __shfl_xor(mx, 2));
  float sum = 0.f;
#pragma unroll
  for (int j = 0; j < 16; ++j) { sv[j] = __expf(sv[j] - mx); sum += sv[j]; }
  sum += __shfl_xor(sum, 1);
  sum += __shfl_xor(sum, 2);
  float inv = 1.f / sum;
  __syncthreads();
#pragma unroll
  for (int j = 0; j < 16; ++j) ks[t * 65 + (sg << 4) + j] = sv[j] * inv;
  __syncthreads();

  const int c0 = sg << 4;
  float outv[16];
#pragma unroll
  for (int j = 0; j < 16; ++j) outv[j] = qs[t * 65 + c0 + j];
  for (int s = 0; s < 64; ++s) {
    float pv = ks[t * 65 + s];
#pragma unroll
    for (int j = 0; j < 16; ++j) outv[j] += pv * vs[s * 65 + c0 + j];
  }
  float* dst = aout + ((size_t)b * 64 + t) * 768 + n * 64 + c0;
#pragma unroll
  for (int j = 0; j < 16; ++j) dst[j] = outv[j];
}

// ---------------------------------------------------------------------------
extern "C" void kernel_launch(void* const* d_in, const int* in_sizes, int n_in,
                              void* d_out, int out_size, void* d_ws, size_t ws_size,
                              hipStream_t stream) {
  const float* x     = (const float*)d_in[0];
  const float* Wqkv  = (const float*)d_in[1];
  const float* Wpq   = (const float*)d_in[2];
  const float* bpq   = (const float*)d_in[3];
  const float* Wpk   = (const float*)d_in[4];
  const float* bpk   = (const float*)d_in[5];
  const float* Wpv   = (const float*)d_in[6];
  const float* bpv   = (const float*)d_in[7];
  const float* gq    = (const float*)d_in[8];
  const float* beq   = (const float*)d_in[9];
  const float* gk    = (const float*)d_in[10];
  const float* bek   = (const float*)d_in[11];
  const float* gv    = (const float*)d_in[12];
  const float* bev   = (const float*)d_in[13];
  const float* relp  = (const float*)d_in[14];
  const float* Wproj = (const float*)d_in[15];
  const float* bproj = (const float*)d_in[16];
  float* out = (float*)d_out;

  unsigned short* u = (unsigned short*)d_ws;
  unsigned short* xbf   = u;                     // 38,535,168
  unsigned short* qkvbf = u + 38535168ull;       // 115,605,504
  unsigned short* WqkvT = u + 154140672ull;      // 1,769,472
  unsigned short* WpTT  = u + 155910144ull;      // 602,112
  float* f = (float*)(u + 156512256ull);
  float* qpool = f;
  float* kpool = f + 786432;
  float* vpool = f + 1572864;
  float* aout  = f + 2359296;

  // conversions / transposes
  cvt_x_k<<<18816, 256, 0, stream>>>(x, xbf, 4816896);
  transpose_cvt_k<<<dim3(24, 72), 256, 0, stream>>>(Wqkv, WqkvT);
  wp_cvt_k<<<784, 256, 0, stream>>>(Wpq, WpTT);
  wp_cvt_k<<<784, 256, 0, stream>>>(Wpk, WpTT + 200704);
  wp_cvt_k<<<784, 256, 0, stream>>>(Wpv, WpTT + 401408);

  // qkv = x @ Wqkv  (bf16 MFMA, Bt layout)
  gemm_bt_mfma_k<<<dim3(18, 392), 256, 0, stream>>>(xbf, WqkvT, qkvbf, 50176, 2304, 768);

  // pooling + bias + LN (bf16 MFMA)
  pool_ln_mfma_k<<<dim3(12, 3, 16), 256, 0, stream>>>(
      qkvbf, WpTT, bpq, bpk, bpv, gq, gk, gv, beq, bek, bev, qpool, kpool, vpool);

  // attention (fp32)
  attention_k<<<dim3(12, 16), 256, 0, stream>>>(qpool, kpool, vpool, relp, aout);

  // final projection (fp32)
  gemm_f32_k<<<dim3(12, 16), 256, 0, stream>>>(aout, Wproj, bproj, out, 1024, 768, 768);
}

// Round 3
// 639.934 us; speedup vs baseline: 4.6151x; 1.1730x over previous
//
#include <hip/hip_runtime.h>

// B=16, T=64, HW=7 (HW2=49), D=768, N=12, C=64, 3D=2304
// x:(B,T,7,7,768) fp32; out:(B,T,768) fp32

typedef __attribute__((ext_vector_type(8))) short bf16x8;
typedef __attribute__((ext_vector_type(4))) float f32x4;
typedef unsigned short ushort_t;

#define AS1U(p) ((const __attribute__((address_space(1))) unsigned int*)(p))
#define AS3U(p) ((__attribute__((address_space(3))) unsigned int*)(p))

__device__ __forceinline__ unsigned short cvt_bf16(float x) {
  union { float f; unsigned int u; } v; v.f = x;
  unsigned int r = v.u + 0x7fffu + ((v.u >> 16) & 1u);
  return (unsigned short)(r >> 16);
}
__device__ __forceinline__ float bf2f(unsigned short h) {
  union { unsigned int u; float f; } v; v.u = ((unsigned int)h) << 16;
  return v.f;
}

// ---------------------------------------------------------------------------
// x fp32 -> bf16 (8 elems/thread)
// ---------------------------------------------------------------------------
__global__ __launch_bounds__(256) void cvt_x_k(const float* __restrict__ src,
                                               unsigned short* __restrict__ dst, int n8) {
  int i = blockIdx.x * 256 + threadIdx.x;
  if (i >= n8) return;
  const float4* s = (const float4*)src + (size_t)i * 2;
  float4 a = s[0], b = s[1];
  ushort4 r0 = { cvt_bf16(a.x), cvt_bf16(a.y), cvt_bf16(a.z), cvt_bf16(a.w) };
  ushort4 r1 = { cvt_bf16(b.x), cvt_bf16(b.y), cvt_bf16(b.z), cvt_bf16(b.w) };
  ushort4* d = (ushort4*)dst + (size_t)i * 2;
  d[0] = r0; d[1] = r1;
}

// ---------------------------------------------------------------------------
// Wqkv [768][2304] fp32 -> WqkvT [2304][768] bf16
// ---------------------------------------------------------------------------
__global__ __launch_bounds__(256) void transpose_cvt_k(const float* __restrict__ src,
                                                       unsigned short* __restrict__ dst) {
  __shared__ float tl[32][33];
  int k0 = blockIdx.x * 32, n0 = blockIdx.y * 32;
  int tx = threadIdx.x & 31, ty = threadIdx.x >> 5;
#pragma unroll
  for (int r = 0; r < 32; r += 8)
    tl[ty + r][tx] = src[(size_t)(k0 + ty + r) * 2304 + n0 + tx];
  __syncthreads();
#pragma unroll
  for (int r = 0; r < 32; r += 8)
    dst[(size_t)(n0 + ty + r) * 768 + k0 + tx] = cvt_bf16(tl[tx][ty + r]);
}

// ---------------------------------------------------------------------------
// Wp [d*3136 + c*49 + hw] fp32 -> WpTT [(hw*64+d)*64 + c] bf16, 50 hw
// (hw=49 zero-padded so the pool kernel's odd-K tail multiplies garbage by 0)
// ---------------------------------------------------------------------------
__global__ __launch_bounds__(256) void wp_cvt_k(const float* __restrict__ src,
                                                unsigned short* __restrict__ dst) {
  int o = blockIdx.x * 256 + threadIdx.x;   // 204800 per p
  if (o >= 204800) return;
  int c = o & 63, d = (o >> 6) & 63, hw = o >> 12;
  dst[o] = (hw < 49) ? cvt_bf16(src[d * 3136 + c * 49 + hw]) : (unsigned short)0;
}

// ---------------------------------------------------------------------------
// relp (127,64) fp32 -> (128,64) bf16, row 127 zeroed
// ---------------------------------------------------------------------------
__global__ __launch_bounds__(256) void relp_cvt_k(const float* __restrict__ src,
                                                  unsigned short* __restrict__ dst) {
  int i = blockIdx.x * 256 + threadIdx.x;   // 8192
  if (i >= 8192) return;
  dst[i] = (i < 8128) ? cvt_bf16(src[i]) : (unsigned short)0;
}

// ---------------------------------------------------------------------------
// MFMA GEMM: C[m][n] = sum_k A[m][k] * Bt[n][k], bf16 in, bf16 out.
// 128x128 tile, BK=32, 256 threads (4 waves 2x2).
// ---------------------------------------------------------------------------
__global__ __launch_bounds__(256) void gemm_bt_mfma_k(
    const unsigned short* __restrict__ A, const unsigned short* __restrict__ Bt,
    unsigned short* __restrict__ Cb, int M, int Nn, int K) {
  __shared__ unsigned short As[128 * 32];
  __shared__ unsigned short Bs[128 * 32];
  const int tid = threadIdx.x;
  const int wave = tid >> 6, lane = tid & 63;
  const int quad = lane >> 4, l16 = lane & 15;
  const int m0 = blockIdx.y * 128, n0 = blockIdx.x * 128;
  const int wm = (wave >> 1) * 64, wn = (wave & 1) * 64;

  const int srow = lane >> 2;
  const int scol = (lane & 3) * 8;
  const unsigned short* Ag0 = A + (size_t)(m0 + wave * 16 + srow) * K + scol;
  const unsigned short* Ag1 = Ag0 + (size_t)64 * K;
  const unsigned short* Bg0 = Bt + (size_t)(n0 + wave * 16 + srow) * K + scol;
  const unsigned short* Bg1 = Bg0 + (size_t)64 * K;
  unsigned short* Asw0 = &As[(wave * 16) * 32];
  unsigned short* Asw1 = &As[(64 + wave * 16) * 32];
  unsigned short* Bsw0 = &Bs[(wave * 16) * 32];
  unsigned short* Bsw1 = &Bs[(64 + wave * 16) * 32];

  f32x4 acc[4][4];
#pragma unroll
  for (int i = 0; i < 4; ++i)
#pragma unroll
    for (int j = 0; j < 4; ++j) acc[i][j] = (f32x4){0.f, 0.f, 0.f, 0.f};

  for (int k0 = 0; k0 < K; k0 += 32) {
    __builtin_amdgcn_global_load_lds(AS1U(Ag0 + k0), AS3U(Asw0), 16, 0, 0);
    __builtin_amdgcn_global_load_lds(AS1U(Ag1 + k0), AS3U(Asw1), 16, 0, 0);
    __builtin_amdgcn_global_load_lds(AS1U(Bg0 + k0), AS3U(Bsw0), 16, 0, 0);
    __builtin_amdgcn_global_load_lds(AS1U(Bg1 + k0), AS3U(Bsw1), 16, 0, 0);
    __syncthreads();
    bf16x8 af[4], bfr[4];
#pragma unroll
    for (int f = 0; f < 4; ++f) {
      af[f]  = *(const bf16x8*)&As[(wm + f * 16 + l16) * 32 + quad * 8];
      bfr[f] = *(const bf16x8*)&Bs[(wn + f * 16 + l16) * 32 + quad * 8];
    }
#pragma unroll
    for (int i = 0; i < 4; ++i)
#pragma unroll
      for (int j = 0; j < 4; ++j)
        acc[i][j] = __builtin_amdgcn_mfma_f32_16x16x32_bf16(af[i], bfr[j], acc[i][j], 0, 0, 0);
    __syncthreads();
  }

#pragma unroll
  for (int i = 0; i < 4; ++i)
#pragma unroll
    for (int j = 0; j < 4; ++j)
#pragma unroll
      for (int r = 0; r < 4; ++r) {
        int row = m0 + wm + i * 16 + quad * 4 + r;
        int col = n0 + wn + j * 16 + l16;
        Cb[(size_t)row * Nn + col] = cvt_bf16(acc[i][j][r]);
      }
}

// ---------------------------------------------------------------------------
// Pool + bias + LayerNorm, MFMA, BK=128 (2 hw per iter, 25 iters).
// Block (n, p, b): out[t=64][d=64] = sum_{hw,c} qkvb[b,t,hw,p,n,c]*WpTT[p,hw,d,c]
// LDS rows are 256B (==0 mod 32 banks) -> chunk XOR-swizzle by (row&15).
// Outputs bf16.
// ---------------------------------------------------------------------------
__global__ __launch_bounds__(256) void pool_ln_mfma_k(
    const unsigned short* __restrict__ qkvb, const unsigned short* __restrict__ WpTT,
    const float* __restrict__ bq, const float* __restrict__ bk, const float* __restrict__ bv,
    const float* __restrict__ gq, const float* __restrict__ gk, const float* __restrict__ gv,
    const float* __restrict__ beq, const float* __restrict__ bek, const float* __restrict__ bev,
    unsigned short* __restrict__ oq, unsigned short* __restrict__ ok_,
    unsigned short* __restrict__ ov) {
  __shared__ unsigned short As[64 * 128];   // [t][2hw x 64c], swizzled
  __shared__ unsigned short Bs[64 * 128];   // [d][2hw x 64c], swizzled
  __shared__ float Ln[64 * 65];
  __shared__ float mu_s[64], rs_s[64];

  const int n = blockIdx.x, p = blockIdx.y, b = blockIdx.z;
  const int tid = threadIdx.x;
  const int wave = tid >> 6, lane = tid & 63;
  const int quad = lane >> 4, l16 = lane & 15;
  const int wm = (wave >> 1) * 32, wn = (wave & 1) * 32;

  const int lr = lane >> 4, lg = lane & 15;
  const size_t abase = ((size_t)b * 3136) * 2304 + (size_t)p * 768 + (size_t)n * 64;
  const unsigned short* WpB = WpTT + (size_t)p * 204800;

  const unsigned short* pA[4];
  const unsigned short* pB[4];
#pragma unroll
  for (int q = 0; q < 4; ++q) {
    int r = wave * 16 + q * 4 + lr;
    int g = lg ^ (r & 15);
    pA[q] = qkvb + abase + (size_t)r * 112896 + (size_t)(g >> 3) * 2304 + (g & 7) * 8;
    pB[q] = WpB + (size_t)(g >> 3) * 4096 + r * 64 + (g & 7) * 8;
  }

  f32x4 acc[2][2];
#pragma unroll
  for (int i = 0; i < 2; ++i)
#pragma unroll
    for (int j = 0; j < 2; ++j) acc[i][j] = (f32x4){0.f, 0.f, 0.f, 0.f};

  for (int it = 0; it < 25; ++it) {
    const size_t offA = (size_t)it * 4608;   // 2*2304
    const size_t offB = (size_t)it * 8192;   // 2*4096
#pragma unroll
    for (int q = 0; q < 4; ++q) {
      __builtin_amdgcn_global_load_lds(AS1U(pA[q] + offA), AS3U(&As[(wave * 16 + q * 4) * 128]), 16, 0, 0);
      __builtin_amdgcn_global_load_lds(AS1U(pB[q] + offB), AS3U(&Bs[(wave * 16 + q * 4) * 128]), 16, 0, 0);
    }
    __syncthreads();
    bf16x8 af[2][4], bfr[2][4];
#pragma unroll
    for (int f = 0; f < 2; ++f) {
      int ra = wm + f * 16 + l16;
      int rb = wn + f * 16 + l16;
#pragma unroll
      for (int ki = 0; ki < 4; ++ki) {
        af[f][ki]  = *(const bf16x8*)&As[ra * 128 + (((ki * 4 + quad) ^ (ra & 15)) * 8)];
        bfr[f][ki] = *(const bf16x8*)&Bs[rb * 128 + (((ki * 4 + quad) ^ (rb & 15)) * 8)];
      }
    }
#pragma unroll
    for (int ki = 0; ki < 4; ++ki)
#pragma unroll
      for (int i = 0; i < 2; ++i)
#pragma unroll
        for (int j = 0; j < 2; ++j)
          acc[i][j] = __builtin_amdgcn_mfma_f32_16x16x32_bf16(af[i][ki], bfr[j][ki], acc[i][j], 0, 0, 0);
    __syncthreads();
  }

  const float* bias = (p == 0) ? bq : (p == 1) ? bk : bv;
  const float* g    = (p == 0) ? gq : (p == 1) ? gk : gv;
  const float* be   = (p == 0) ? beq : (p == 1) ? bek : bev;
  unsigned short* outp = (p == 0) ? oq : (p == 1) ? ok_ : ov;

#pragma unroll
  for (int i = 0; i < 2; ++i)
#pragma unroll
    for (int j = 0; j < 2; ++j)
#pragma unroll
      for (int r = 0; r < 4; ++r) {
        int t = wm + i * 16 + quad * 4 + r;
        int d = wn + j * 16 + l16;
        Ln[t * 65 + d] = acc[i][j][r] + bias[d];
      }
  __syncthreads();
  if (tid < 64) {
    float s = 0.f;
#pragma unroll 8
    for (int c = 0; c < 64; ++c) s += Ln[tid * 65 + c];
    float m = s * (1.f / 64.f);
    float v2 = 0.f;
#pragma unroll 8
    for (int c = 0; c < 64; ++c) { float dl = Ln[tid * 65 + c] - m; v2 += dl * dl; }
    mu_s[tid] = m;
    rs_s[tid] = rsqrtf(v2 * (1.f / 64.f) + 1e-5f);
  }
  __syncthreads();
  {
    int t = tid >> 2, d0 = (tid & 3) * 16;
    float m = mu_s[t], rv = rs_s[t];
    unsigned short ob[16];
#pragma unroll
    for (int j = 0; j < 16; ++j)
      ob[j] = cvt_bf16((Ln[t * 65 + d0 + j] - m) * rv * g[d0 + j] + be[d0 + j]);
    unsigned short* dst = outp + ((size_t)(b * 12 + n) * 64 + t) * 64 + d0;
    *(uint4*)dst = *(uint4*)ob;
    *(uint4*)(dst + 8) = *(uint4*)(ob + 8);
  }
}

// ---------------------------------------------------------------------------
// Fused MFMA attention per (b,n): S = scale*qk^T + gather(q@relp^T),
// softmax fp32, O = P@v + q. Inputs bf16, output fp32 in (b,t,n,c) layout.
// ---------------------------------------------------------------------------
__global__ __launch_bounds__(256) void attn_mfma_k(
    const unsigned short* __restrict__ qp, const unsigned short* __restrict__ kp,
    const unsigned short* __restrict__ vp, const unsigned short* __restrict__ relb,
    float* __restrict__ aout) {
  __shared__ unsigned short qs[64 * 64];
  __shared__ unsigned short ks[64 * 64];
  __shared__ unsigned short vt[64 * 64];   // v transposed: [c][s]
  __shared__ unsigned short rs[128 * 64];  // relp bf16, row127 = 0
  __shared__ float Gs[64 * 128];           // G[t][u]
  __shared__ unsigned short Ps[64 * 64];   // P bf16

  const int n = blockIdx.x, b = blockIdx.y;
  const int tid = threadIdx.x;
  const size_t base = ((size_t)b * 12 + n) * 4096;

  for (int i = tid; i < 512; i += 256) {
    ((uint4*)qs)[i] = ((const uint4*)(qp + base))[i];
    ((uint4*)ks)[i] = ((const uint4*)(kp + base))[i];
  }
  for (int i = tid; i < 1024; i += 256)
    ((uint4*)rs)[i] = ((const uint4*)relb)[i];
  {
    int s = tid >> 2, c0 = (tid & 3) * 16;
    unsigned short tmp[16];
    *(uint4*)tmp = *(const uint4*)(vp + base + s * 64 + c0);
    *(uint4*)(tmp + 8) = *(const uint4*)(vp + base + s * 64 + c0 + 8);
#pragma unroll
    for (int i = 0; i < 16; ++i) vt[(c0 + i) * 64 + s] = tmp[i];
  }
  __syncthreads();

  const int wave = tid >> 6, lane = tid & 63;
  const int quad = lane >> 4, l16 = lane & 15;
  const int tm = wave * 16;

  bf16x8 aq[2];
  aq[0] = *(const bf16x8*)&qs[(tm + l16) * 64 + quad * 8];
  aq[1] = *(const bf16x8*)&qs[(tm + l16) * 64 + quad * 8 + 32];

  f32x4 accqk[4], accg[8];
#pragma unroll
  for (int j = 0; j < 4; ++j) accqk[j] = (f32x4){0.f, 0.f, 0.f, 0.f};
#pragma unroll
  for (int j = 0; j < 8; ++j) accg[j] = (f32x4){0.f, 0.f, 0.f, 0.f};

#pragma unroll
  for (int ki = 0; ki < 2; ++ki) {
#pragma unroll
    for (int j = 0; j < 4; ++j) {
      bf16x8 bk = *(const bf16x8*)&ks[(j * 16 + l16) * 64 + quad * 8 + ki * 32];
      accqk[j] = __builtin_amdgcn_mfma_f32_16x16x32_bf16(aq[ki], bk, accqk[j], 0, 0, 0);
    }
#pragma unroll
    for (int j = 0; j < 8; ++j) {
      bf16x8 br = *(const bf16x8*)&rs[(j * 16 + l16) * 64 + quad * 8 + ki * 32];
      accg[j] = __builtin_amdgcn_mfma_f32_16x16x32_bf16(aq[ki], br, accg[j], 0, 0, 0);
    }
  }
#pragma unroll
  for (int j = 0; j < 8; ++j)
#pragma unroll
    for (int r = 0; r < 4; ++r)
      Gs[(tm + quad * 4 + r) * 128 + j * 16 + l16] = accg[j][r];
  __syncthreads();

  // softmax (rows tm+quad*4+r, cols j*16+l16); reduce across the 16 l16 lanes
#pragma unroll
  for (int r = 0; r < 4; ++r) {
    int t = tm + quad * 4 + r;
    float sv[4];
#pragma unroll
    for (int j = 0; j < 4; ++j) {
      int s = j * 16 + l16;
      sv[j] = 0.125f * accqk[j][r] + Gs[t * 128 + (t + 63 - s)];
    }
    float m = fmaxf(fmaxf(sv[0], sv[1]), fmaxf(sv[2], sv[3]));
    m = fmaxf(m, __shfl_xor(m, 1));
    m = fmaxf(m, __shfl_xor(m, 2));
    m = fmaxf(m, __shfl_xor(m, 4));
    m = fmaxf(m, __shfl_xor(m, 8));
    float e[4], sum = 0.f;
#pragma unroll
    for (int j = 0; j < 4; ++j) { e[j] = __expf(sv[j] - m); sum += e[j]; }
    sum += __shfl_xor(sum, 1);
    sum += __shfl_xor(sum, 2);
    sum += __shfl_xor(sum, 4);
    sum += __shfl_xor(sum, 8);
    float inv = 1.f / sum;
#pragma unroll
    for (int j = 0; j < 4; ++j)
      Ps[t * 64 + j * 16 + l16] = cvt_bf16(e[j] * inv);
  }
  __syncthreads();

  // O = P @ v (+q residual)
  bf16x8 ap[2];
  ap[0] = *(const bf16x8*)&Ps[(tm + l16) * 64 + quad * 8];
  ap[1] = *(const bf16x8*)&Ps[(tm + l16) * 64 + quad * 8 + 32];
  f32x4 acco[4];
#pragma unroll
  for (int j = 0; j < 4; ++j) acco[j] = (f32x4){0.f, 0.f, 0.f, 0.f};
#pragma unroll
  for (int ki = 0; ki < 2; ++ki)
#pragma unroll
    for (int j = 0; j < 4; ++j) {
      bf16x8 bv = *(const bf16x8*)&vt[(j * 16 + l16) * 64 + quad * 8 + ki * 32];
      acco[j] = __builtin_amdgcn_mfma_f32_16x16x32_bf16(ap[ki], bv, acco[j], 0, 0, 0);
    }
#pragma unroll
  for (int j = 0; j < 4; ++j)
#pragma unroll
    for (int r = 0; r < 4; ++r) {
      int t = tm + quad * 4 + r;
      int c = j * 16 + l16;
      float o = acco[j][r] + bf2f(qs[t * 64 + c]);
      aout[((size_t)b * 64 + t) * 768 + n * 64 + c] = o;
    }
}

// ---------------------------------------------------------------------------
// fp32 GEMM (final projection): C[m,n] = sum_k A[m,k]*B[k,n] + bias[n]
// ---------------------------------------------------------------------------
__global__ __launch_bounds__(256) void gemm_f32_k(
    const float* __restrict__ A, const float* __restrict__ Bm,
    const float* __restrict__ bias, float* __restrict__ Cm,
    int M, int Nn, int K) {
  __shared__ float As[16][68];
  __shared__ float Bs[16][64];
  const int tid = threadIdx.x;
  const int ty = tid >> 4, tx = tid & 15;
  const int m0 = blockIdx.y * 64, n0 = blockIdx.x * 64;

  const int la_m = tid >> 2;
  const int la_k = (tid & 3) << 2;
  const int lb_k = tid >> 4;
  const int lb_n = (tid & 15) << 2;

  const float* Ap = A + (size_t)(m0 + la_m) * K + la_k;
  const float* Bp = Bm + (size_t)lb_k * Nn + n0 + lb_n;

  float acc[4][4];
#pragma unroll
  for (int i = 0; i < 4; ++i)
#pragma unroll
    for (int j = 0; j < 4; ++j) acc[i][j] = 0.f;

  for (int k0 = 0; k0 < K; k0 += 16) {
    float4 av = *(const float4*)(Ap + k0);
    float4 bv = *(const float4*)(Bp + (size_t)k0 * Nn);
    As[la_k + 0][la_m] = av.x;
    As[la_k + 1][la_m] = av.y;
    As[la_k + 2][la_m] = av.z;
    As[la_k + 3][la_m] = av.w;
    *(float4*)&Bs[lb_k][lb_n] = bv;
    __syncthreads();
#pragma unroll
    for (int kk = 0; kk < 16; ++kk) {
      float af[4], bf[4];
      *(float4*)af = *(const float4*)&As[kk][ty << 2];
      *(float4*)bf = *(const float4*)&Bs[kk][tx << 2];
#pragma unroll
      for (int i = 0; i < 4; ++i)
#pragma unroll
        for (int j = 0; j < 4; ++j) acc[i][j] += af[i] * bf[j];
    }
    __syncthreads();
  }

  float bb[4] = {0.f, 0.f, 0.f, 0.f};
  if (bias) {
#pragma unroll
    for (int j = 0; j < 4; ++j) bb[j] = bias[n0 + (tx << 2) + j];
  }
#pragma unroll
  for (int i = 0; i < 4; ++i) {
    float4 o;
    o.x = acc[i][0] + bb[0];
    o.y = acc[i][1] + bb[1];
    o.z = acc[i][2] + bb[2];
    o.w = acc[i][3] + bb[3];
    *(float4*)(Cm + (size_t)(m0 + (ty << 2) + i) * Nn + n0 + (tx << 2)) = o;
  }
}

// ---------------------------------------------------------------------------
extern "C" void kernel_launch(void* const* d_in, const int* in_sizes, int n_in,
                              void* d_out, int out_size, void* d_ws, size_t ws_size,
                              hipStream_t stream) {
  const float* x     = (const float*)d_in[0];
  const float* Wqkv  = (const float*)d_in[1];
  const float* Wpq   = (const float*)d_in[2];
  const float* bpq   = (const float*)d_in[3];
  const float* Wpk   = (const float*)d_in[4];
  const float* bpk   = (const float*)d_in[5];
  const float* Wpv   = (const float*)d_in[6];
  const float* bpv   = (const float*)d_in[7];
  const float* gq    = (const float*)d_in[8];
  const float* beq   = (const float*)d_in[9];
  const float* gk    = (const float*)d_in[10];
  const float* bek   = (const float*)d_in[11];
  const float* gv    = (const float*)d_in[12];
  const float* bev   = (const float*)d_in[13];
  const float* relp  = (const float*)d_in[14];
  const float* Wproj = (const float*)d_in[15];
  const float* bproj = (const float*)d_in[16];
  float* out = (float*)d_out;

  unsigned short* u = (unsigned short*)d_ws;
  unsigned short* xbf   = u;                       // 38,535,168
  unsigned short* qkvbf = u + 38535168ull;         // 115,605,504
  unsigned short* WqkvT = u + 154140672ull;        // 1,769,472
  unsigned short* WpTT  = u + 155910144ull;        // 3*204800 = 614,400
  unsigned short* relb  = u + 156524544ull;        // 8,192
  unsigned short* qpb   = u + 156532736ull;        // 786,432
  unsigned short* kpb   = u + 157319168ull;        // 786,432
  unsigned short* vpb   = u + 158105600ull;        // 786,432
  float* aout = (float*)(u + 158892032ull);        // 786,432 floats

  cvt_x_k<<<18816, 256, 0, stream>>>(x, xbf, 4816896);
  transpose_cvt_k<<<dim3(24, 72), 256, 0, stream>>>(Wqkv, WqkvT);
  wp_cvt_k<<<800, 256, 0, stream>>>(Wpq, WpTT);
  wp_cvt_k<<<800, 256, 0, stream>>>(Wpk, WpTT + 204800);
  wp_cvt_k<<<800, 256, 0, stream>>>(Wpv, WpTT + 409600);
  relp_cvt_k<<<32, 256, 0, stream>>>(relp, relb);

  gemm_bt_mfma_k<<<dim3(18, 392), 256, 0, stream>>>(xbf, WqkvT, qkvbf, 50176, 2304, 768);

  pool_ln_mfma_k<<<dim3(12, 3, 16), 256, 0, stream>>>(
      qkvbf, WpTT, bpq, bpk, bpv, gq, gk, gv, beq, bek, bev, qpb, kpb, vpb);

  attn_mfma_k<<<dim3(12, 16), 256, 0, stream>>>(qpb, kpb, vpb, relb, aout);

  gemm_f32_k<<<dim3(12, 16), 256, 0, stream>>>(aout, Wproj, bproj, out, 1024, 768, 768);
}

// Round 8
// 633.594 us; speedup vs baseline: 4.6613x; 1.0100x over previous
//
#include <hip/hip_runtime.h>

// B=16, T=64, HW=7 (HW2=49), D=768, N=12, C=64, 3D=2304
// x:(B,T,7,7,768) fp32; out:(B,T,768) fp32
// R3-verified pipeline + XCD-swizzled qkv GEMM (bitwise-identical math).

typedef __attribute__((ext_vector_type(8))) short bf16x8;
typedef __attribute__((ext_vector_type(4))) float f32x4;

#define AS1U(p) ((const __attribute__((address_space(1))) unsigned int*)(p))
#define AS3U(p) ((__attribute__((address_space(3))) unsigned int*)(p))

__device__ __forceinline__ unsigned short cvt_bf16(float x) {
  union { float f; unsigned int u; } v; v.f = x;
  unsigned int r = v.u + 0x7fffu + ((v.u >> 16) & 1u);
  return (unsigned short)(r >> 16);
}
__device__ __forceinline__ float bf2f(unsigned short h) {
  union { unsigned int u; float f; } v; v.u = ((unsigned int)h) << 16;
  return v.f;
}

// ---------------------------------------------------------------------------
// fp32 -> bf16 (8 elems/thread)
// ---------------------------------------------------------------------------
__global__ __launch_bounds__(256) void cvt_x_k(const float* __restrict__ src,
                                               unsigned short* __restrict__ dst, int n8) {
  int i = blockIdx.x * 256 + threadIdx.x;
  if (i >= n8) return;
  const float4* s = (const float4*)src + (size_t)i * 2;
  float4 a = s[0], b = s[1];
  ushort4 r0 = { cvt_bf16(a.x), cvt_bf16(a.y), cvt_bf16(a.z), cvt_bf16(a.w) };
  ushort4 r1 = { cvt_bf16(b.x), cvt_bf16(b.y), cvt_bf16(b.z), cvt_bf16(b.w) };
  ushort4* d = (ushort4*)dst + (size_t)i * 2;
  d[0] = r0; d[1] = r1;
}

// ---------------------------------------------------------------------------
// Wqkv [768][2304] fp32 -> WqkvT [2304][768] bf16
// ---------------------------------------------------------------------------
__global__ __launch_bounds__(256) void transpose_cvt_k(const float* __restrict__ src,
                                                       unsigned short* __restrict__ dst) {
  __shared__ float tl[32][33];
  int k0 = blockIdx.x * 32, n0 = blockIdx.y * 32;
  int tx = threadIdx.x & 31, ty = threadIdx.x >> 5;
#pragma unroll
  for (int r = 0; r < 32; r += 8)
    tl[ty + r][tx] = src[(size_t)(k0 + ty + r) * 2304 + n0 + tx];
  __syncthreads();
#pragma unroll
  for (int r = 0; r < 32; r += 8)
    dst[(size_t)(n0 + ty + r) * 768 + k0 + tx] = cvt_bf16(tl[tx][ty + r]);
}

// ---------------------------------------------------------------------------
// Wp [d*3136 + c*49 + hw] fp32 -> WpTT [(hw*64+d)*64 + c] bf16 (50 hw, pad 0)
// ---------------------------------------------------------------------------
__global__ __launch_bounds__(256) void wp_cvt_k(const float* __restrict__ src,
                                                unsigned short* __restrict__ dst) {
  int o = blockIdx.x * 256 + threadIdx.x;   // 204800 per p
  if (o >= 204800) return;
  int c = o & 63, d = (o >> 6) & 63, hw = o >> 12;
  dst[o] = (hw < 49) ? cvt_bf16(src[d * 3136 + c * 49 + hw]) : (unsigned short)0;
}

// ---------------------------------------------------------------------------
// relp (127,64) fp32 -> (128,64) bf16, row 127 zeroed
// ---------------------------------------------------------------------------
__global__ __launch_bounds__(256) void relp_cvt_k(const float* __restrict__ src,
                                                  unsigned short* __restrict__ dst) {
  int i = blockIdx.x * 256 + threadIdx.x;   // 8192
  if (i >= 8192) return;
  dst[i] = (i < 8128) ? cvt_bf16(src[i]) : (unsigned short)0;
}

// ---------------------------------------------------------------------------
// qkv GEMM (R3-verified body): C[m][n] = sum_k A[m][k]*Bt[n][k], bf16 out.
// M=50176, N=2304, K=768. 128x128 tile, BK=32, 4 waves.
// 1-D grid 7056 with XCD swizzle: xcd = L&7 owns m-rows [xcd*49, xcd*49+49),
// n fastest within each m-row -> A-row fetched once per XCD, B hot in L2.
// ---------------------------------------------------------------------------
__global__ __launch_bounds__(256) void gemm_qkv_k(
    const unsigned short* __restrict__ A, const unsigned short* __restrict__ Bt,
    unsigned short* __restrict__ Cb) {
  __shared__ unsigned short As[128 * 32];
  __shared__ unsigned short Bs[128 * 32];
  const int L = blockIdx.x;                 // 0..7055
  const int xcd = L & 7;
  const int slot = L >> 3;                  // 0..881
  const int nb = slot % 18;
  const int mb = xcd * 49 + slot / 18;      // 0..391
  const int m0 = mb * 128, n0 = nb * 128;
  const int K = 768, Nn = 2304;

  const int tid = threadIdx.x;
  const int wave = tid >> 6, lane = tid & 63;
  const int quad = lane >> 4, l16 = lane & 15;
  const int wm = (wave >> 1) * 64, wn = (wave & 1) * 64;

  const int srow = lane >> 2;
  const int scol = (lane & 3) * 8;
  const unsigned short* Ag0 = A + (size_t)(m0 + wave * 16 + srow) * K + scol;
  const unsigned short* Ag1 = Ag0 + (size_t)64 * K;
  const unsigned short* Bg0 = Bt + (size_t)(n0 + wave * 16 + srow) * K + scol;
  const unsigned short* Bg1 = Bg0 + (size_t)64 * K;
  unsigned short* Asw0 = &As[(wave * 16) * 32];
  unsigned short* Asw1 = &As[(64 + wave * 16) * 32];
  unsigned short* Bsw0 = &Bs[(wave * 16) * 32];
  unsigned short* Bsw1 = &Bs[(64 + wave * 16) * 32];

  f32x4 acc[4][4];
#pragma unroll
  for (int i = 0; i < 4; ++i)
#pragma unroll
    for (int j = 0; j < 4; ++j) acc[i][j] = (f32x4){0.f, 0.f, 0.f, 0.f};

  for (int k0 = 0; k0 < K; k0 += 32) {
    __builtin_amdgcn_global_load_lds(AS1U(Ag0 + k0), AS3U(Asw0), 16, 0, 0);
    __builtin_amdgcn_global_load_lds(AS1U(Ag1 + k0), AS3U(Asw1), 16, 0, 0);
    __builtin_amdgcn_global_load_lds(AS1U(Bg0 + k0), AS3U(Bsw0), 16, 0, 0);
    __builtin_amdgcn_global_load_lds(AS1U(Bg1 + k0), AS3U(Bsw1), 16, 0, 0);
    __syncthreads();
    bf16x8 af[4], bfr[4];
#pragma unroll
    for (int f = 0; f < 4; ++f) {
      af[f]  = *(const bf16x8*)&As[(wm + f * 16 + l16) * 32 + quad * 8];
      bfr[f] = *(const bf16x8*)&Bs[(wn + f * 16 + l16) * 32 + quad * 8];
    }
#pragma unroll
    for (int i = 0; i < 4; ++i)
#pragma unroll
      for (int j = 0; j < 4; ++j)
        acc[i][j] = __builtin_amdgcn_mfma_f32_16x16x32_bf16(af[i], bfr[j], acc[i][j], 0, 0, 0);
    __syncthreads();
  }

#pragma unroll
  for (int i = 0; i < 4; ++i)
#pragma unroll
    for (int j = 0; j < 4; ++j)
#pragma unroll
      for (int r = 0; r < 4; ++r) {
        int row = m0 + wm + i * 16 + quad * 4 + r;
        int col = n0 + wn + j * 16 + l16;
        Cb[(size_t)row * Nn + col] = cvt_bf16(acc[i][j][r]);
      }
}

// ---------------------------------------------------------------------------
// Pool + bias + LayerNorm, MFMA, BK=128 (2 hw per iter, 25 iters) — R3-verified.
// Block (n, p, b): out[t=64][d=64] = sum_{hw,c} qkvb[b,t,hw,p,n,c]*WpTT[p,hw,d,c]
// Outputs bf16 in (b,n,t,d).
// ---------------------------------------------------------------------------
__global__ __launch_bounds__(256) void pool_ln_mfma_k(
    const unsigned short* __restrict__ qkvb, const unsigned short* __restrict__ WpTT,
    const float* __restrict__ bq, const float* __restrict__ bk, const float* __restrict__ bv,
    const float* __restrict__ gq, const float* __restrict__ gk, const float* __restrict__ gv,
    const float* __restrict__ beq, const float* __restrict__ bek, const float* __restrict__ bev,
    unsigned short* __restrict__ oq, unsigned short* __restrict__ ok_,
    unsigned short* __restrict__ ov) {
  __shared__ unsigned short As[64 * 128];
  __shared__ unsigned short Bs[64 * 128];
  __shared__ float Ln[64 * 65];
  __shared__ float mu_s[64], rs_s[64];

  const int n = blockIdx.x, p = blockIdx.y, b = blockIdx.z;
  const int tid = threadIdx.x;
  const int wave = tid >> 6, lane = tid & 63;
  const int quad = lane >> 4, l16 = lane & 15;
  const int wm = (wave >> 1) * 32, wn = (wave & 1) * 32;

  const int lr = lane >> 4, lg = lane & 15;
  const size_t abase = ((size_t)b * 3136) * 2304 + (size_t)p * 768 + (size_t)n * 64;
  const unsigned short* WpB = WpTT + (size_t)p * 204800;

  const unsigned short* pA[4];
  const unsigned short* pB[4];
#pragma unroll
  for (int q = 0; q < 4; ++q) {
    int r = wave * 16 + q * 4 + lr;
    int g = lg ^ (r & 15);
    pA[q] = qkvb + abase + (size_t)r * 112896 + (size_t)(g >> 3) * 2304 + (g & 7) * 8;
    pB[q] = WpB + (size_t)(g >> 3) * 4096 + r * 64 + (g & 7) * 8;
  }

  f32x4 acc[2][2];
#pragma unroll
  for (int i = 0; i < 2; ++i)
#pragma unroll
    for (int j = 0; j < 2; ++j) acc[i][j] = (f32x4){0.f, 0.f, 0.f, 0.f};

  for (int it = 0; it < 25; ++it) {
    const size_t offA = (size_t)it * 4608;
    const size_t offB = (size_t)it * 8192;
#pragma unroll
    for (int q = 0; q < 4; ++q) {
      __builtin_amdgcn_global_load_lds(AS1U(pA[q] + offA), AS3U(&As[(wave * 16 + q * 4) * 128]), 16, 0, 0);
      __builtin_amdgcn_global_load_lds(AS1U(pB[q] + offB), AS3U(&Bs[(wave * 16 + q * 4) * 128]), 16, 0, 0);
    }
    __syncthreads();
    bf16x8 af[2][4], bfr[2][4];
#pragma unroll
    for (int f = 0; f < 2; ++f) {
      int ra = wm + f * 16 + l16;
      int rb = wn + f * 16 + l16;
#pragma unroll
      for (int ki = 0; ki < 4; ++ki) {
        af[f][ki]  = *(const bf16x8*)&As[ra * 128 + (((ki * 4 + quad) ^ (ra & 15)) * 8)];
        bfr[f][ki] = *(const bf16x8*)&Bs[rb * 128 + (((ki * 4 + quad) ^ (rb & 15)) * 8)];
      }
    }
#pragma unroll
    for (int ki = 0; ki < 4; ++ki)
#pragma unroll
      for (int i = 0; i < 2; ++i)
#pragma unroll
        for (int j = 0; j < 2; ++j)
          acc[i][j] = __builtin_amdgcn_mfma_f32_16x16x32_bf16(af[i][ki], bfr[j][ki], acc[i][j], 0, 0, 0);
    __syncthreads();
  }

  const float* bias = (p == 0) ? bq : (p == 1) ? bk : bv;
  const float* g    = (p == 0) ? gq : (p == 1) ? gk : gv;
  const float* be   = (p == 0) ? beq : (p == 1) ? bek : bev;
  unsigned short* outp = (p == 0) ? oq : (p == 1) ? ok_ : ov;

#pragma unroll
  for (int i = 0; i < 2; ++i)
#pragma unroll
    for (int j = 0; j < 2; ++j)
#pragma unroll
      for (int r = 0; r < 4; ++r) {
        int t = wm + i * 16 + quad * 4 + r;
        int d = wn + j * 16 + l16;
        Ln[t * 65 + d] = acc[i][j][r] + bias[d];
      }
  __syncthreads();
  if (tid < 64) {
    float s = 0.f;
#pragma unroll 8
    for (int c = 0; c < 64; ++c) s += Ln[tid * 65 + c];
    float m = s * (1.f / 64.f);
    float v2 = 0.f;
#pragma unroll 8
    for (int c = 0; c < 64; ++c) { float dl = Ln[tid * 65 + c] - m; v2 += dl * dl; }
    mu_s[tid] = m;
    rs_s[tid] = rsqrtf(v2 * (1.f / 64.f) + 1e-5f);
  }
  __syncthreads();
  {
    int t = tid >> 2, d0 = (tid & 3) * 16;
    float m = mu_s[t], rv = rs_s[t];
    unsigned short ob[16];
#pragma unroll
    for (int j = 0; j < 16; ++j)
      ob[j] = cvt_bf16((Ln[t * 65 + d0 + j] - m) * rv * g[d0 + j] + be[d0 + j]);
    unsigned short* dst = outp + ((size_t)(b * 12 + n) * 64 + t) * 64 + d0;
    *(uint4*)dst = *(uint4*)ob;
    *(uint4*)(dst + 8) = *(uint4*)(ob + 8);
  }
}

// ---------------------------------------------------------------------------
// Fused MFMA attention per (b,n) — R3-verified verbatim.
// ---------------------------------------------------------------------------
__global__ __launch_bounds__(256) void attn_mfma_k(
    const unsigned short* __restrict__ qp, const unsigned short* __restrict__ kp,
    const unsigned short* __restrict__ vp, const unsigned short* __restrict__ relb,
    float* __restrict__ aout) {
  __shared__ unsigned short qs[64 * 64];
  __shared__ unsigned short ks[64 * 64];
  __shared__ unsigned short vt[64 * 64];
  __shared__ unsigned short rs[128 * 64];
  __shared__ float Gs[64 * 128];
  __shared__ unsigned short Ps[64 * 64];

  const int n = blockIdx.x, b = blockIdx.y;
  const int tid = threadIdx.x;
  const size_t base = ((size_t)b * 12 + n) * 4096;

  for (int i = tid; i < 512; i += 256) {
    ((uint4*)qs)[i] = ((const uint4*)(qp + base))[i];
    ((uint4*)ks)[i] = ((const uint4*)(kp + base))[i];
  }
  for (int i = tid; i < 1024; i += 256)
    ((uint4*)rs)[i] = ((const uint4*)relb)[i];
  {
    int s = tid >> 2, c0 = (tid & 3) * 16;
    unsigned short tmp[16];
    *(uint4*)tmp = *(const uint4*)(vp + base + s * 64 + c0);
    *(uint4*)(tmp + 8) = *(const uint4*)(vp + base + s * 64 + c0 + 8);
#pragma unroll
    for (int i = 0; i < 16; ++i) vt[(c0 + i) * 64 + s] = tmp[i];
  }
  __syncthreads();

  const int wave = tid >> 6, lane = tid & 63;
  const int quad = lane >> 4, l16 = lane & 15;
  const int tm = wave * 16;

  bf16x8 aq[2];
  aq[0] = *(const bf16x8*)&qs[(tm + l16) * 64 + quad * 8];
  aq[1] = *(const bf16x8*)&qs[(tm + l16) * 64 + quad * 8 + 32];

  f32x4 accqk[4], accg[8];
#pragma unroll
  for (int j = 0; j < 4; ++j) accqk[j] = (f32x4){0.f, 0.f, 0.f, 0.f};
#pragma unroll
  for (int j = 0; j < 8; ++j) accg[j] = (f32x4){0.f, 0.f, 0.f, 0.f};

#pragma unroll
  for (int ki = 0; ki < 2; ++ki) {
#pragma unroll
    for (int j = 0; j < 4; ++j) {
      bf16x8 bk = *(const bf16x8*)&ks[(j * 16 + l16) * 64 + quad * 8 + ki * 32];
      accqk[j] = __builtin_amdgcn_mfma_f32_16x16x32_bf16(aq[ki], bk, accqk[j], 0, 0, 0);
    }
#pragma unroll
    for (int j = 0; j < 8; ++j) {
      bf16x8 br = *(const bf16x8*)&rs[(j * 16 + l16) * 64 + quad * 8 + ki * 32];
      accg[j] = __builtin_amdgcn_mfma_f32_16x16x32_bf16(aq[ki], br, accg[j], 0, 0, 0);
    }
  }
#pragma unroll
  for (int j = 0; j < 8; ++j)
#pragma unroll
    for (int r = 0; r < 4; ++r)
      Gs[(tm + quad * 4 + r) * 128 + j * 16 + l16] = accg[j][r];
  __syncthreads();

#pragma unroll
  for (int r = 0; r < 4; ++r) {
    int t = tm + quad * 4 + r;
    float sv[4];
#pragma unroll
    for (int j = 0; j < 4; ++j) {
      int s = j * 16 + l16;
      sv[j] = 0.125f * accqk[j][r] + Gs[t * 128 + (t + 63 - s)];
    }
    float m = fmaxf(fmaxf(sv[0], sv[1]), fmaxf(sv[2], sv[3]));
    m = fmaxf(m, __shfl_xor(m, 1));
    m = fmaxf(m, __shfl_xor(m, 2));
    m = fmaxf(m, __shfl_xor(m, 4));
    m = fmaxf(m, __shfl_xor(m, 8));
    float e[4], sum = 0.f;
#pragma unroll
    for (int j = 0; j < 4; ++j) { e[j] = __expf(sv[j] - m); sum += e[j]; }
    sum += __shfl_xor(sum, 1);
    sum += __shfl_xor(sum, 2);
    sum += __shfl_xor(sum, 4);
    sum += __shfl_xor(sum, 8);
    float inv = 1.f / sum;
#pragma unroll
    for (int j = 0; j < 4; ++j)
      Ps[t * 64 + j * 16 + l16] = cvt_bf16(e[j] * inv);
  }
  __syncthreads();

  bf16x8 ap[2];
  ap[0] = *(const bf16x8*)&Ps[(tm + l16) * 64 + quad * 8];
  ap[1] = *(const bf16x8*)&Ps[(tm + l16) * 64 + quad * 8 + 32];
  f32x4 acco[4];
#pragma unroll
  for (int j = 0; j < 4; ++j) acco[j] = (f32x4){0.f, 0.f, 0.f, 0.f};
#pragma unroll
  for (int ki = 0; ki < 2; ++ki)
#pragma unroll
    for (int j = 0; j < 4; ++j) {
      bf16x8 bv = *(const bf16x8*)&vt[(j * 16 + l16) * 64 + quad * 8 + ki * 32];
      acco[j] = __builtin_amdgcn_mfma_f32_16x16x32_bf16(ap[ki], bv, acco[j], 0, 0, 0);
    }
#pragma unroll
  for (int j = 0; j < 4; ++j)
#pragma unroll
    for (int r = 0; r < 4; ++r) {
      int t = tm + quad * 4 + r;
      int c = j * 16 + l16;
      float o = acco[j][r] + bf2f(qs[t * 64 + c]);
      aout[((size_t)b * 64 + t) * 768 + n * 64 + c] = o;
    }
}

// ---------------------------------------------------------------------------
// fp32 GEMM (final projection): C[m,n] = sum_k A[m,k]*B[k,n] + bias[n]
// ---------------------------------------------------------------------------
__global__ __launch_bounds__(256) void gemm_f32_k(
    const float* __restrict__ A, const float* __restrict__ Bm,
    const float* __restrict__ bias, float* __restrict__ Cm,
    int M, int Nn, int K) {
  __shared__ float As[16][68];
  __shared__ float Bs[16][64];
  const int tid = threadIdx.x;
  const int ty = tid >> 4, tx = tid & 15;
  const int m0 = blockIdx.y * 64, n0 = blockIdx.x * 64;

  const int la_m = tid >> 2;
  const int la_k = (tid & 3) << 2;
  const int lb_k = tid >> 4;
  const int lb_n = (tid & 15) << 2;

  const float* Ap = A + (size_t)(m0 + la_m) * K + la_k;
  const float* Bp = Bm + (size_t)lb_k * Nn + n0 + lb_n;

  float acc[4][4];
#pragma unroll
  for (int i = 0; i < 4; ++i)
#pragma unroll
    for (int j = 0; j < 4; ++j) acc[i][j] = 0.f;

  for (int k0 = 0; k0 < K; k0 += 16) {
    float4 av = *(const float4*)(Ap + k0);
    float4 bv = *(const float4*)(Bp + (size_t)k0 * Nn);
    As[la_k + 0][la_m] = av.x;
    As[la_k + 1][la_m] = av.y;
    As[la_k + 2][la_m] = av.z;
    As[la_k + 3][la_m] = av.w;
    *(float4*)&Bs[lb_k][lb_n] = bv;
    __syncthreads();
#pragma unroll
    for (int kk = 0; kk < 16; ++kk) {
      float af[4], bf[4];
      *(float4*)af = *(const float4*)&As[kk][ty << 2];
      *(float4*)bf = *(const float4*)&Bs[kk][tx << 2];
#pragma unroll
      for (int i = 0; i < 4; ++i)
#pragma unroll
        for (int j = 0; j < 4; ++j) acc[i][j] += af[i] * bf[j];
    }
    __syncthreads();
  }

  float bb[4] = {0.f, 0.f, 0.f, 0.f};
  if (bias) {
#pragma unroll
    for (int j = 0; j < 4; ++j) bb[j] = bias[n0 + (tx << 2) + j];
  }
#pragma unroll
  for (int i = 0; i < 4; ++i) {
    float4 o;
    o.x = acc[i][0] + bb[0];
    o.y = acc[i][1] + bb[1];
    o.z = acc[i][2] + bb[2];
    o.w = acc[i][3] + bb[3];
    *(float4*)(Cm + (size_t)(m0 + (ty << 2) + i) * Nn + n0 + (tx << 2)) = o;
  }
}

// ---------------------------------------------------------------------------
extern "C" void kernel_launch(void* const* d_in, const int* in_sizes, int n_in,
                              void* d_out, int out_size, void* d_ws, size_t ws_size,
                              hipStream_t stream) {
  const float* x     = (const float*)d_in[0];
  const float* Wqkv  = (const float*)d_in[1];
  const float* Wpq   = (const float*)d_in[2];
  const float* bpq   = (const float*)d_in[3];
  const float* Wpk   = (const float*)d_in[4];
  const float* bpk   = (const float*)d_in[5];
  const float* Wpv   = (const float*)d_in[6];
  const float* bpv   = (const float*)d_in[7];
  const float* gq    = (const float*)d_in[8];
  const float* beq   = (const float*)d_in[9];
  const float* gk    = (const float*)d_in[10];
  const float* bek   = (const float*)d_in[11];
  const float* gv    = (const float*)d_in[12];
  const float* bev   = (const float*)d_in[13];
  const float* relp  = (const float*)d_in[14];
  const float* Wproj = (const float*)d_in[15];
  const float* bproj = (const float*)d_in[16];
  float* out = (float*)d_out;

  unsigned short* u = (unsigned short*)d_ws;
  unsigned short* xbf   = u;                       // 38,535,168 us
  unsigned short* qkvbf = u + 38535168ull;         // 115,605,504 us
  unsigned short* WqkvT = u + 154140672ull;        // 1,769,472 us
  unsigned short* WpTT  = u + 155910144ull;        // 614,400 us
  unsigned short* relb  = u + 156524544ull;        // 8,192 us
  unsigned short* qpb   = u + 156532736ull;        // 786,432 us
  unsigned short* kpb   = u + 157319168ull;        // 786,432 us
  unsigned short* vpb   = u + 158105600ull;        // 786,432 us
  float* aout = (float*)(u + 158892032ull);        // 786,432 f32

  cvt_x_k<<<18816, 256, 0, stream>>>(x, xbf, 4816896);
  transpose_cvt_k<<<dim3(24, 72), 256, 0, stream>>>(Wqkv, WqkvT);
  wp_cvt_k<<<800, 256, 0, stream>>>(Wpq, WpTT);
  wp_cvt_k<<<800, 256, 0, stream>>>(Wpk, WpTT + 204800);
  wp_cvt_k<<<800, 256, 0, stream>>>(Wpv, WpTT + 409600);
  relp_cvt_k<<<32, 256, 0, stream>>>(relp, relb);

  // qkv = x @ Wqkv (bf16 MFMA, XCD-swizzled 1-D grid)
  gemm_qkv_k<<<7056, 256, 0, stream>>>(xbf, WqkvT, qkvbf);

  // pooling + bias + LN (bf16 MFMA)
  pool_ln_mfma_k<<<dim3(12, 3, 16), 256, 0, stream>>>(
      qkvbf, WpTT, bpq, bpk, bpv, gq, gk, gv, beq, bek, bev, qpb, kpb, vpb);

  // attention (MFMA)
  attn_mfma_k<<<dim3(12, 16), 256, 0, stream>>>(qpb, kpb, vpb, relb, aout);

  // final projection (fp32)
  gemm_f32_k<<<dim3(12, 16), 256, 0, stream>>>(aout, Wproj, bproj, out, 1024, 768, 768);
}